// Round 11
// baseline (9596.952 us; speedup 1.0000x reference)
//
#include <hip/hip_runtime.h>
#include <math.h>

#define BB_   64
#define TT_   256
#define DIN_  256
#define HH_   512
#define NMEM_ 128
#define WWID_ 64
#define RR_   4
#define DOUT_ 256
#define CTRL_ 512
#define EPSV  1e-8f
#define NBLK  256
#define NTHR  512
#define OSTR  456   // W_intT4 o-stride
#define MPAD  65    // padded mem stride

__device__ __forceinline__ float sigm(float x){ return 1.f/(1.f+expf(-x)); }
__device__ __forceinline__ float softp(float x){ return (x>20.f)? x : log1pf(expf(x)); }
__device__ __forceinline__ float wredsum(float v){
  #pragma unroll
  for (int o=32;o>0;o>>=1) v += __shfl_xor(v,o,64);
  return v;
}
__device__ __forceinline__ float wredmax(float v){
  #pragma unroll
  for (int o=32;o>0;o>>=1) v = fmaxf(v, __shfl_xor(v,o,64));
  return v;
}

// ---- LLC-coherent accessors: relaxed agent-scope atomics (bypass per-XCD L2) ----
__device__ __forceinline__ float2 cload2(const float* p){
  unsigned long long u = __hip_atomic_load((const unsigned long long*)p,
                          __ATOMIC_RELAXED, __HIP_MEMORY_SCOPE_AGENT);
  float2 r; __builtin_memcpy(&r, &u, 8); return r;
}
__device__ __forceinline__ void cstore2(float* p, float2 v){
  unsigned long long u; __builtin_memcpy(&u, &v, 8);
  __hip_atomic_store((unsigned long long*)p, u, __ATOMIC_RELAXED,
                     __HIP_MEMORY_SCOPE_AGENT);
}
__device__ __forceinline__ void cstore1(float* p, float v){
  unsigned u; __builtin_memcpy(&u, &v, 4);
  __hip_atomic_store((unsigned*)p, u, __ATOMIC_RELAXED, __HIP_MEMORY_SCOPE_AGENT);
}

// ---- fence-free grid barrier: monotonic counters, 32 groups x 8 blocks ----
__device__ __forceinline__ void gridbar(unsigned* bar, unsigned k)
{
  __syncthreads();
  if (threadIdx.x == 0) {
    const int g = blockIdx.x >> 3;
    unsigned a = __hip_atomic_fetch_add(bar + g*32, 1u, __ATOMIC_RELAXED,
                                        __HIP_MEMORY_SCOPE_AGENT);
    bool released = false;
    if (a == 8u*k - 1u) {
      unsigned r = __hip_atomic_fetch_add(bar + 1024, 1u, __ATOMIC_RELAXED,
                                          __HIP_MEMORY_SCOPE_AGENT);
      if (r == 32u*k - 1u) {
        __hip_atomic_store(bar + 1056, k, __ATOMIC_RELAXED,
                           __HIP_MEMORY_SCOPE_AGENT);
        released = true;
      }
    }
    if (!released) {
      while (__hip_atomic_load(bar + 1056, __ATOMIC_RELAXED,
                               __HIP_MEMORY_SCOPE_AGENT) < k)
        __builtin_amdgcn_s_sleep(1);
    }
  }
  __syncthreads();
}

__global__ void k_initbar(unsigned* bar){
  int i = blockIdx.x*256 + threadIdx.x;
  if (i < 1088)
    __hip_atomic_store(bar + i, 0u, __ATOMIC_RELAXED, __HIP_MEMORY_SCOPE_AGENT);
}

// one-time: W_intT4[kq][o][c] = W_int[o][4kq+c]
__global__ void k_prep_w(const float* __restrict__ Wint, float* __restrict__ WiT4){
  const int o  = blockIdx.x;
  const int kq = threadIdx.x;
  float4 v = *(const float4*)(Wint + (size_t)o*HH_ + 4*kq);
  *(float4*)(WiT4 + ((size_t)kq*OSTR + o)*4) = v;
}

struct Params {
  const float *x, *Wih, *Whh, *bih, *bhh, *bint, *Wout, *bout;
  float *out;
  float *xbuf;   // 2*16384 fallback x staging
  float *hp;     // 2*32768 (h packed [j/4][b][4])
  float *rvp;    // 16384
  float *WiT4;   // 128*456*4
  float *xT;     // 256*64*64*4 = 16 MB (if useXT)
  unsigned *bar;
  int useXT;
};

union __align__(16) SMu {
  float redA[8][8][64];         // 16 KB gates reduction
  float redO[4][4][64];
  float tile[64][65];           // init transpose tile (16.6 KB)
  struct {
    float hS[HH_];
    float ifcS[OSTR];
    float kpk[WWID_][8];
    float dH[4][NMEM_];
    float qH[4][NMEM_];
    float nH[4][NMEM_];
    float drH[4][RR_][NMEM_];
    float wwS[NMEM_];
    float rwS[RR_][NMEM_];
    float rvH[8][64];
    float scal[8];
    float red2[8];
  } c;
};

__launch_bounds__(NTHR, 2)
__global__ void k_persist(Params p)
{
  __shared__ SMu sm;
  __shared__ float memS[NMEM_][MPAD];

  const int bi  = blockIdx.x;
  const int tid = threadIdx.x;
  const int b   = tid & 63;
  const int wv  = tid >> 6;            // 0..7
  const int j0  = bi*2;
  const int bb  = bi;

  float c_reg = 0.f;

  int rowoff[8];                       // weight row offsets (floats)
  #pragma unroll
  for (int r = 0; r < 8; ++r)
    rowoff[r] = ((r>>1)*HH_ + j0 + (r&1))*CTRL_;

  float bsum[4];
  if (tid < 128) {
    const int j = j0 + (tid >> 6);
    #pragma unroll
    for (int g = 0; g < 4; ++g)
      bsum[g] = p.bih[g*HH_ + j] + p.bhh[g*HH_ + j];
  }
  float bintR = 0.f;
  if (bi < 64 && tid < 453) bintR = p.bint[tid];

  // ---- init: zero h0/rv, zero memS, stage x ----
  {
    const float2 zz = make_float2(0.f, 0.f);
    const int gt = bi*NTHR + tid;
    if      (gt < 16384) cstore2(p.hp  + 2*gt,         zz);
    else if (gt < 24576) cstore2(p.rvp + 2*(gt-16384), zz);
    if (bi < 64)
      for (int i = tid; i < NMEM_*MPAD; i += NTHR)
        ((float*)memS)[i] = 0.f;
    if (p.useXT) {
      // block bi transposes timestep t=bi into xT[t][kq][b][4]
      const int lane = tid & 63, rg = tid >> 6;
      for (int q = 0; q < 4; ++q) {
        const int k0 = q*64;
        #pragma unroll
        for (int i = 0; i < 8; ++i) {
          const int brow = rg + i*8;
          sm.tile[brow][lane] =
            p.x[(size_t)brow*(TT_*DIN_) + (size_t)bi*DIN_ + k0 + lane];
        }
        __syncthreads();
        #pragma unroll
        for (int pp = 0; pp < 2; ++pp) {
          const int idx = tid + 512*pp;
          const int kql = idx >> 6, b2 = idx & 63;
          float* d = p.xT + ((size_t)(bi*64 + q*16 + kql)*64 + b2)*4;
          cstore2(d,   make_float2(sm.tile[b2][4*kql],   sm.tile[b2][4*kql+1]));
          cstore2(d+2, make_float2(sm.tile[b2][4*kql+2], sm.tile[b2][4*kql+3]));
        }
        __syncthreads();
      }
    } else if (bi >= 64 && bi < 128 && tid < 64) {
      const int B = bi - 64;
      float4 v = *(const float4*)(p.x + (size_t)B*(TT_*DIN_) + 4*tid);
      float* d = p.xbuf + tid*256 + B*4;
      cstore2(d,   make_float2(v.x, v.y));
      cstore2(d+2, make_float2(v.z, v.w));
    }
  }
  unsigned bk = 1;
  gridbar(p.bar, bk);

  for (int t = 0; t < TT_; ++t) {
    const int cur = t & 1, nxt = cur ^ 1;
    const float* hR = p.hp + cur*32768;
    float*       hW = p.hp + nxt*32768;

    // ================= Phase A: gates GEMM + LSTM =================
    {
      float acc[8];
      #pragma unroll
      for (int r = 0; r < 8; ++r) acc[r] = 0.f;

      // --- x part: 8 quads (cached xT or fallback xbuf) ---
      {
        const float* wX = p.Wih + 32*wv;
        if (p.useXT) {
          const float* xsrc = p.xT + ((size_t)(t*64 + 8*wv)*64 + b)*4;
          #pragma unroll
          for (int kk = 0; kk < 8; ++kk) {
            float4 a = *(const float4*)(xsrc + kk*256);   // plain, L1/L2-cached
            #pragma unroll
            for (int r = 0; r < 8; ++r) {
              float4 w = *(const float4*)(wX + rowoff[r] + (kk<<2));
              acc[r] += w.x*a.x + w.y*a.y + w.z*a.z + w.w*a.w;
            }
          }
        } else {
          const float* xsrc = p.xbuf + cur*16384 + (8*wv*64 + b)*4;
          #pragma unroll
          for (int kk = 0; kk < 8; ++kk) {
            float2 alo = cload2(xsrc + kk*256);
            float2 ahi = cload2(xsrc + kk*256 + 2);
            #pragma unroll
            for (int r = 0; r < 8; ++r) {
              float4 w = *(const float4*)(wX + rowoff[r] + (kk<<2));
              acc[r] += w.x*alo.x + w.y*alo.y + w.z*ahi.x + w.w*ahi.y;
            }
          }
        }
      }
      // --- rv part: 8 quads (LLC) ---
      {
        const float* wR = p.Wih + 256 + 32*wv;
        const float* rsrc = p.rvp + (8*wv*64 + b)*4;
        #pragma unroll
        for (int kk = 0; kk < 8; ++kk) {
          float2 alo = cload2(rsrc + kk*256);
          float2 ahi = cload2(rsrc + kk*256 + 2);
          #pragma unroll
          for (int r = 0; r < 8; ++r) {
            float4 w = *(const float4*)(wR + rowoff[r] + (kk<<2));
            acc[r] += w.x*alo.x + w.y*alo.y + w.z*ahi.x + w.w*ahi.y;
          }
        }
      }
      // --- h part: 16 quads (LLC) ---
      {
        const float* wH = p.Whh + 64*wv;
        const float* hsrc = hR + (16*wv*64 + b)*4;
        #pragma unroll
        for (int kk = 0; kk < 16; ++kk) {
          float2 alo = cload2(hsrc + kk*256);
          float2 ahi = cload2(hsrc + kk*256 + 2);
          #pragma unroll
          for (int r = 0; r < 8; ++r) {
            float4 w = *(const float4*)(wH + rowoff[r] + (kk<<2));
            acc[r] += w.x*alo.x + w.y*alo.y + w.z*ahi.x + w.w*ahi.y;
          }
        }
      }
      #pragma unroll
      for (int r = 0; r < 8; ++r) sm.redA[wv][r][b] = acc[r];
      __syncthreads();

      if (tid < 128) {
        const int jj = tid >> 6;
        const int j  = j0 + jj;
        float gs[4];
        #pragma unroll
        for (int g = 0; g < 4; ++g) {
          float s = bsum[g];
          #pragma unroll
          for (int w8 = 0; w8 < 8; ++w8) s += sm.redA[w8][g*2+jj][b];
          gs[g] = s;
        }
        float cn = sigm(gs[1])*c_reg + sigm(gs[0])*tanhf(gs[2]);
        c_reg = cn;
        float hn = sigm(gs[3])*tanhf(cn);
        cstore1(hW + (j>>2)*256 + b*4 + (j&3), hn);
      }
    }
    gridbar(p.bar, ++bk);

    // ====== Phase BC: iface (in-block, transposed W) + addressing ======
    if (bi < 64) {
      if (tid < 128) {
        const float* hsrc = hW + tid*256 + bb*4;
        float2 lo = cload2(hsrc), hi = cload2(hsrc + 2);
        sm.c.hS[4*tid]   = lo.x; sm.c.hS[4*tid+1] = lo.y;
        sm.c.hS[4*tid+2] = hi.x; sm.c.hS[4*tid+3] = hi.y;
      }
      __syncthreads();
      {
        const int o = (tid < 453) ? tid : 452;
        float a0 = bintR, a1 = 0.f, a2 = 0.f, a3 = 0.f;   // 4-way ILP chain
        #pragma unroll 8
        for (int kq = 0; kq < 128; ++kq) {
          float4 w  = *(const float4*)(p.WiT4 + ((size_t)kq*OSTR + o)*4);
          float4 h4 = *(const float4*)&sm.c.hS[kq << 2];
          a0 += w.x*h4.x; a1 += w.y*h4.y; a2 += w.z*h4.z; a3 += w.w*h4.w;
        }
        if (tid < 453) sm.c.ifcS[tid] = (a0 + a1) + (a2 + a3);
      }
      __syncthreads();

      // key pack + key norms (wave 0)
      if (tid < 64) {
        const int w = tid;
        float wk = sm.c.ifcS[260+w];
        float q0 = sm.c.ifcS[w],      q1 = sm.c.ifcS[64+w];
        float q2 = sm.c.ifcS[128+w],  q3 = sm.c.ifcS[192+w];
        float er  = sigm(sm.c.ifcS[325+w]);
        float wvc = sm.c.ifcS[389+w];
        sm.c.kpk[w][0]=wk; sm.c.kpk[w][1]=q0; sm.c.kpk[w][2]=q1; sm.c.kpk[w][3]=q2;
        sm.c.kpk[w][4]=q3; sm.c.kpk[w][5]=er; sm.c.kpk[w][6]=wvc; sm.c.kpk[w][7]=0.f;
        float s0 = wredsum(wk*wk);
        float s1 = wredsum(q0*q0);
        float s2 = wredsum(q1*q1);
        float s3 = wredsum(q2*q2);
        float s4 = wredsum(q3*q3);
        if (w == 0) {
          sm.c.scal[0] = fmaxf(sqrtf(s0), EPSV);
          sm.c.scal[1] = fmaxf(sqrtf(s1), EPSV);
          sm.c.scal[2] = fmaxf(sqrtf(s2), EPSV);
          sm.c.scal[3] = fmaxf(sqrtf(s3), EPSV);
          sm.c.scal[4] = fmaxf(sqrtf(s4), EPSV);
        }
      }
      __syncthreads();

      const int n  = tid & 127;
      const int wh = tid >> 7;

      // pass1: write-key dot + pre-update norm
      {
        float dotw = 0.f, q = 0.f;
        const int w0 = wh*16;
        #pragma unroll
        for (int w = 0; w < 16; ++w) {
          float m = memS[n][w0+w];
          dotw += sm.c.kpk[w0+w][0]*m;
          q    += m*m;
        }
        sm.c.dH[wh][n] = dotw;
        sm.c.qH[wh][n] = q;
      }
      __syncthreads();

      // write softmax over 128 slots
      float a_n = 0.f, e_n = 0.f;
      const float wstr = softp(sm.c.ifcS[324]) + 1.f;
      if (tid < 128) {
        float dot = sm.c.dH[0][n] + sm.c.dH[1][n] + sm.c.dH[2][n] + sm.c.dH[3][n];
        float q2  = sm.c.qH[0][n] + sm.c.qH[1][n] + sm.c.qH[2][n] + sm.c.qH[3][n];
        a_n = wstr * dot / (sm.c.scal[0] * fmaxf(sqrtf(q2), EPSV));
        float mx = wredmax(a_n);
        if ((tid & 63) == 0) sm.c.red2[tid>>6] = mx;
      }
      __syncthreads();
      if (tid < 128) {
        float mx = fmaxf(sm.c.red2[0], sm.c.red2[1]);
        e_n = expf(a_n - mx);
        float s = wredsum(e_n);
        if ((tid & 63) == 0) sm.c.red2[4 + (tid>>6)] = s;
      }
      __syncthreads();
      if (tid < 128)
        sm.c.wwS[n] = e_n / (sm.c.red2[4] + sm.c.red2[5]);
      __syncthreads();

      // pass2: memory update + read-key dots + post norm
      {
        float ww_n = sm.c.wwS[n];
        float nrm=0.f, d0=0.f, d1=0.f, d2=0.f, d3=0.f;
        const int w0 = wh*16;
        #pragma unroll
        for (int w = 0; w < 16; ++w) {
          float4 k0 = *(const float4*)&sm.c.kpk[w0+w][0];
          float4 k1 = *(const float4*)&sm.c.kpk[w0+w][4];
          float m  = memS[n][w0+w];
          float mn = m*(1.f - ww_n*k1.y) + ww_n*k1.z;
          memS[n][w0+w] = mn;
          nrm += mn*mn;
          d0 += k0.y*mn; d1 += k0.z*mn; d2 += k0.w*mn; d3 += k1.x*mn;
        }
        sm.c.nH[wh][n] = nrm;
        sm.c.drH[wh][0][n]=d0; sm.c.drH[wh][1][n]=d1;
        sm.c.drH[wh][2][n]=d2; sm.c.drH[wh][3][n]=d3;
      }
      __syncthreads();

      // read scores
      if (tid < 128) {
        float nrm = sm.c.nH[0][n] + sm.c.nH[1][n] + sm.c.nH[2][n] + sm.c.nH[3][n];
        float inm = 1.f / fmaxf(sqrtf(nrm), EPSV);
        #pragma unroll
        for (int r = 0; r < RR_; ++r) {
          float rstr = softp(sm.c.ifcS[256+r]) + 1.f;
          float dr = sm.c.drH[0][r][n] + sm.c.drH[1][r][n]
                   + sm.c.drH[2][r][n] + sm.c.drH[3][r][n];
          sm.c.rwS[r][n] = rstr * dr * inm / sm.c.scal[1+r];
        }
      }
      __syncthreads();

      // read softmaxes: waves 0..3 = heads
      if (tid < 256) {
        float v0 = sm.c.rwS[wv][b], v1 = sm.c.rwS[wv][b+64];
        float mx = wredmax(fmaxf(v0, v1));
        float e0 = expf(v0-mx), e1 = expf(v1-mx);
        float s  = wredsum(e0+e1);
        sm.c.rwS[wv][b]    = e0/s;
        sm.c.rwS[wv][b+64] = e1/s;
      }
      __syncthreads();

      // rv partials: wave wv -> head wv>>1, n-half wv&1
      {
        const int r  = wv >> 1;
        const int n0 = (wv & 1) * 64;
        float acc = 0.f;
        #pragma unroll 4
        for (int n2 = n0; n2 < n0 + 64; n2 += 4) {
          float4 r4 = *(const float4*)&sm.c.rwS[r][n2];
          acc += r4.x*memS[n2][b]   + r4.y*memS[n2+1][b]
               + r4.z*memS[n2+2][b] + r4.w*memS[n2+3][b];
        }
        sm.c.rvH[wv][b] = acc;
      }
      __syncthreads();
      if (tid < 256) {
        const int r = tid >> 6;
        float acc = sm.c.rvH[2*r][b] + sm.c.rvH[2*r+1][b];
        const int k = r*64 + b;
        cstore1(p.rvp + (k>>2)*256 + bb*4 + (k&3), acc);
      }
    } else if (!p.useXT && bi < 128) {
      if (t+1 < TT_ && tid < 64) {
        const int B = bi - 64;
        float4 v = *(const float4*)(p.x + (size_t)B*(TT_*DIN_)
                                    + (size_t)(t+1)*DIN_ + 4*tid);
        float* d = p.xbuf + nxt*16384 + tid*256 + B*4;
        cstore2(d,   make_float2(v.x, v.y));
        cstore2(d+2, make_float2(v.z, v.w));
      }
    }
    gridbar(p.bar, ++bk);
  }

  // ================= Output projection (last step only) =================
  if (bi < 64) {
    const int o0 = bi*4;
    if (tid < 256) {
      float acc[4] = {0.f, 0.f, 0.f, 0.f};
      #pragma unroll 4
      for (int kk = 0; kk < 48; ++kk) {
        const int k = wv*192 + kk*4;
        const float* a8 = (k < 512)
          ? (p.hp  + (((k    )>>2)*64 + b)*4)
          : (p.rvp + (((k-512)>>2)*64 + b)*4);
        float2 alo = cload2(a8);
        float2 ahi = cload2(a8 + 2);
        #pragma unroll
        for (int r = 0; r < 4; ++r) {
          float4 w = *(const float4*)(p.Wout + (size_t)(o0+r)*(HH_ + RR_*WWID_) + k);
          acc[r] += w.x*alo.x + w.y*alo.y + w.z*ahi.x + w.w*ahi.y;
        }
      }
      #pragma unroll
      for (int r = 0; r < 4; ++r) sm.redO[wv][r][b] = acc[r];
    }
    __syncthreads();
    if (tid < 64) {
      float4 o4;
      float* po = (float*)&o4;
      #pragma unroll
      for (int r = 0; r < 4; ++r)
        po[r] = sm.redO[0][r][b] + sm.redO[1][r][b] + sm.redO[2][r][b]
              + sm.redO[3][r][b] + p.bout[o0+r];
      *(float4*)(p.out + (size_t)b*DOUT_ + o0) = o4;
    }
  }
}

extern "C" void kernel_launch(void* const* d_in, const int* in_sizes, int n_in,
                              void* d_out, int out_size, void* d_ws, size_t ws_size,
                              hipStream_t stream)
{
  Params prm;
  prm.x    = (const float*)d_in[0];
  prm.Wih  = (const float*)d_in[1];
  prm.Whh  = (const float*)d_in[2];
  prm.bih  = (const float*)d_in[3];
  prm.bhh  = (const float*)d_in[4];
  const float* Wint = (const float*)d_in[5];
  prm.bint = (const float*)d_in[6];
  prm.Wout = (const float*)d_in[7];
  prm.bout = (const float*)d_in[8];
  prm.out  = (float*)d_out;

  float* ws = (float*)d_ws;
  size_t off = 0;
  prm.xbuf = ws + off; off += 2*16384;
  prm.hp   = ws + off; off += 2*32768;
  prm.rvp  = ws + off; off += 16384;
  prm.WiT4 = ws + off; off += (size_t)128*OSTR*4;
  prm.bar  = (unsigned*)(ws + off); off += 2048;
  prm.xT   = ws + off;
  const size_t needXT = (off + (size_t)TT_*64*64*4) * sizeof(float);
  prm.useXT = (ws_size >= needXT) ? 1 : 0;

  k_prep_w<<<453, 128, 0, stream>>>(Wint, prm.WiT4);
  k_initbar<<<5, 256, 0, stream>>>(prm.bar);
  k_persist<<<NBLK, NTHR, 0, stream>>>(prm);
}

// Round 12
// 8561.510 us; speedup vs baseline: 1.1209x; 1.1209x over previous
//
#include <hip/hip_runtime.h>
#include <math.h>

#define BB_   64
#define TT_   256
#define DIN_  256
#define HH_   512
#define NMEM_ 128
#define WWID_ 64
#define RR_   4
#define DOUT_ 256
#define CTRL_ 512
#define EPSV  1e-8f
#define NBLK  256
#define NTHR  512
#define OSTR  456   // W_intT4 o-stride
#define MPAD  65    // padded mem stride

__device__ __forceinline__ float sigm(float x){ return 1.f/(1.f+expf(-x)); }
__device__ __forceinline__ float softp(float x){ return (x>20.f)? x : log1pf(expf(x)); }
__device__ __forceinline__ float wredsum(float v){
  #pragma unroll
  for (int o=32;o>0;o>>=1) v += __shfl_xor(v,o,64);
  return v;
}
__device__ __forceinline__ float wredmax(float v){
  #pragma unroll
  for (int o=32;o>0;o>>=1) v = fmaxf(v, __shfl_xor(v,o,64));
  return v;
}

// ---- LLC-coherent accessors: relaxed agent-scope atomics (bypass per-XCD L2) ----
__device__ __forceinline__ float2 cload2(const float* p){
  unsigned long long u = __hip_atomic_load((const unsigned long long*)p,
                          __ATOMIC_RELAXED, __HIP_MEMORY_SCOPE_AGENT);
  float2 r; __builtin_memcpy(&r, &u, 8); return r;
}
__device__ __forceinline__ void cstore2(float* p, float2 v){
  unsigned long long u; __builtin_memcpy(&u, &v, 8);
  __hip_atomic_store((unsigned long long*)p, u, __ATOMIC_RELAXED,
                     __HIP_MEMORY_SCOPE_AGENT);
}
__device__ __forceinline__ void cstore1(float* p, float v){
  unsigned u; __builtin_memcpy(&u, &v, 4);
  __hip_atomic_store((unsigned*)p, u, __ATOMIC_RELAXED, __HIP_MEMORY_SCOPE_AGENT);
}

// ---- fence-free grid barrier: monotonic counters, 32 groups x 8 blocks ----
__device__ __forceinline__ void gridbar(unsigned* bar, unsigned k)
{
  __syncthreads();
  if (threadIdx.x == 0) {
    const int g = blockIdx.x >> 3;
    unsigned a = __hip_atomic_fetch_add(bar + g*32, 1u, __ATOMIC_RELAXED,
                                        __HIP_MEMORY_SCOPE_AGENT);
    bool released = false;
    if (a == 8u*k - 1u) {
      unsigned r = __hip_atomic_fetch_add(bar + 1024, 1u, __ATOMIC_RELAXED,
                                          __HIP_MEMORY_SCOPE_AGENT);
      if (r == 32u*k - 1u) {
        __hip_atomic_store(bar + 1056, k, __ATOMIC_RELAXED,
                           __HIP_MEMORY_SCOPE_AGENT);
        released = true;
      }
    }
    if (!released) {
      while (__hip_atomic_load(bar + 1056, __ATOMIC_RELAXED,
                               __HIP_MEMORY_SCOPE_AGENT) < k)
        __builtin_amdgcn_s_sleep(1);
    }
  }
  __syncthreads();
}

__global__ void k_initbar(unsigned* bar){
  int i = blockIdx.x*256 + threadIdx.x;
  if (i < 1088)
    __hip_atomic_store(bar + i, 0u, __ATOMIC_RELAXED, __HIP_MEMORY_SCOPE_AGENT);
}

// one-time: W_intT4[kq][o][c] = W_int[o][4kq+c]
__global__ void k_prep_w(const float* __restrict__ Wint, float* __restrict__ WiT4){
  const int o  = blockIdx.x;
  const int kq = threadIdx.x;
  float4 v = *(const float4*)(Wint + (size_t)o*HH_ + 4*kq);
  *(float4*)(WiT4 + ((size_t)kq*OSTR + o)*4) = v;
}

struct Params {
  const float *x, *Wih, *Whh, *bih, *bhh, *bint, *Wout, *bout;
  float *out;
  float *hp;     // 2*32768 (h packed [j/4][b][4])
  float *rvp;    // 16384
  float *WiT4;   // 128*456*4
  unsigned *bar;
};

union __align__(16) SMu {
  struct {
    float4 actS[2048];          // 32 KB: [kq][bl] staged activations (8 batches)
    float  red[4][4][16][8];    // 8 KB:  [ks][g][jl][bl] K-partials
  } a;
  float redO[4][4][64];
  struct {
    float hS[HH_];
    float ifcS[OSTR];
    float kpk[WWID_][8];
    float dH[4][NMEM_];
    float qH[4][NMEM_];
    float nH[4][NMEM_];
    float drH[4][RR_][NMEM_];
    float wwS[NMEM_];
    float rwS[RR_][NMEM_];
    float rvH[8][64];
    float scal[8];
    float red2[8];
  } c;
};

__launch_bounds__(NTHR, 2)
__global__ void k_persist(Params p)
{
  __shared__ SMu sm;
  __shared__ float memS[NMEM_][MPAD];

  const int bi  = blockIdx.x;
  const int tid = threadIdx.x;
  const int b   = tid & 63;            // BC/epilogue lane
  const int wv  = tid >> 6;            // BC/epilogue wave
  const int rg  = bi & 31;             // row-group: 16 hidden units
  const int col = bi >> 5;             // batch-group: 8 batches
  const int j0  = rg*16;
  const int B0  = col*8;
  const int bb  = bi;                  // BC batch id (bi<64)

  // Phase A thread mapping
  const int ksA = tid >> 7;            // 0..3 K-slice
  const int jlA = (tid >> 3) & 15;     // 0..15 hidden unit
  const int blA = tid & 7;             // 0..7 batch lane

  float c_reg = 0.f;                   // LSTM cell state (tid<128: (jl,bl))

  // gate-weight row pointers for (ksA, jlA): 4 gates
  const float* wbg[4];
  {
    const float* wsrc = (ksA < 2) ? p.Wih : p.Whh;
    const int koff = (ksA & 1) * 256;
    #pragma unroll
    for (int g = 0; g < 4; ++g)
      wbg[g] = wsrc + (size_t)(g*HH_ + j0 + jlA)*CTRL_ + koff;
  }

  float bsum[4];
  if (tid < 128) {
    const int j = j0 + (tid >> 3);
    #pragma unroll
    for (int g = 0; g < 4; ++g)
      bsum[g] = p.bih[g*HH_ + j] + p.bhh[g*HH_ + j];
  }
  float bintR = 0.f;
  if (bi < 64 && tid < 453) bintR = p.bint[tid];

  // ---- init: zero h0/rv, zero memS ----
  {
    const float2 zz = make_float2(0.f, 0.f);
    const int gt = bi*NTHR + tid;
    if      (gt < 16384) cstore2(p.hp  + 2*gt,         zz);
    else if (gt < 24576) cstore2(p.rvp + 2*(gt-16384), zz);
    if (bi < 64)
      for (int i = tid; i < NMEM_*MPAD; i += NTHR)
        ((float*)memS)[i] = 0.f;
  }
  unsigned bk = 1;
  gridbar(p.bar, bk);

  for (int t = 0; t < TT_; ++t) {
    const int cur = t & 1, nxt = cur ^ 1;
    const float* hR = p.hp + cur*32768;
    float*       hW = p.hp + nxt*32768;

    // ================= Phase A: gates GEMM + LSTM =================
    {
      // stage acts for this block's 8 batches: actS[kq][bl] (idx = kq*8+bl)
      #pragma unroll
      for (int i = 0; i < 4; ++i) {
        const int idx = tid + 512*i;
        const int kq = idx >> 3, bl = idx & 7, bg = B0 + bl;
        float4 v;
        if (kq < 64) {               // x: immutable input, plain cached load
          v = *(const float4*)(p.x + (size_t)bg*(TT_*DIN_)
                               + (size_t)t*DIN_ + kq*4);
        } else if (kq < 128) {       // rv: LLC-coherent
          const float* s = p.rvp + (kq-64)*256 + bg*4;
          float2 lo = cload2(s), hi = cload2(s + 2);
          v = make_float4(lo.x, lo.y, hi.x, hi.y);
        } else {                     // h: LLC-coherent
          const float* s = hR + (kq-128)*256 + bg*4;
          float2 lo = cload2(s), hi = cload2(s + 2);
          v = make_float4(lo.x, lo.y, hi.x, hi.y);
        }
        sm.a.actS[idx] = v;
      }
      __syncthreads();

      float4 ac[4];
      #pragma unroll
      for (int g = 0; g < 4; ++g) ac[g] = make_float4(0.f, 0.f, 0.f, 0.f);

      const int kbase = ksA*64;
      #pragma unroll 4
      for (int i = 0; i < 64; ++i) {
        float4 a = sm.a.actS[(kbase + i)*8 + blA];   // b128 broadcast, no conflict
        #pragma unroll
        for (int g = 0; g < 4; ++g) {
          float4 w = *(const float4*)(wbg[g] + (i << 2));  // uniform, L2-warm
          ac[g].x += w.x*a.x; ac[g].y += w.y*a.y;
          ac[g].z += w.z*a.z; ac[g].w += w.w*a.w;
        }
      }
      #pragma unroll
      for (int g = 0; g < 4; ++g)
        sm.a.red[ksA][g][jlA][blA] = (ac[g].x + ac[g].y) + (ac[g].z + ac[g].w);
      __syncthreads();

      if (tid < 128) {
        const int jl = tid >> 3, bl = tid & 7;
        float gs[4];
        #pragma unroll
        for (int g = 0; g < 4; ++g)
          gs[g] = sm.a.red[0][g][jl][bl] + sm.a.red[1][g][jl][bl]
                + sm.a.red[2][g][jl][bl] + sm.a.red[3][g][jl][bl] + bsum[g];
        float cn = sigm(gs[1])*c_reg + sigm(gs[0])*tanhf(gs[2]);
        c_reg = cn;
        float hn = sigm(gs[3])*tanhf(cn);
        const int j = j0 + jl, bg = B0 + bl;
        cstore1(hW + (j>>2)*256 + bg*4 + (j&3), hn);
      }
    }
    gridbar(p.bar, ++bk);

    // ====== Phase BC: iface (in-block, transposed W) + addressing ======
    if (bi < 64) {
      if (tid < 128) {
        const float* hsrc = hW + tid*256 + bb*4;
        float2 lo = cload2(hsrc), hi = cload2(hsrc + 2);
        sm.c.hS[4*tid]   = lo.x; sm.c.hS[4*tid+1] = lo.y;
        sm.c.hS[4*tid+2] = hi.x; sm.c.hS[4*tid+3] = hi.y;
      }
      __syncthreads();
      {
        const int o = (tid < 453) ? tid : 452;
        float a0 = bintR, a1 = 0.f, a2 = 0.f, a3 = 0.f;
        #pragma unroll 8
        for (int kq = 0; kq < 128; ++kq) {
          float4 w  = *(const float4*)(p.WiT4 + ((size_t)kq*OSTR + o)*4);
          float4 h4 = *(const float4*)&sm.c.hS[kq << 2];
          a0 += w.x*h4.x; a1 += w.y*h4.y; a2 += w.z*h4.z; a3 += w.w*h4.w;
        }
        if (tid < 453) sm.c.ifcS[tid] = (a0 + a1) + (a2 + a3);
      }
      __syncthreads();

      // key pack + key norms (wave 0)
      if (tid < 64) {
        const int w = tid;
        float wk = sm.c.ifcS[260+w];
        float q0 = sm.c.ifcS[w],      q1 = sm.c.ifcS[64+w];
        float q2 = sm.c.ifcS[128+w],  q3 = sm.c.ifcS[192+w];
        float er  = sigm(sm.c.ifcS[325+w]);
        float wvc = sm.c.ifcS[389+w];
        sm.c.kpk[w][0]=wk; sm.c.kpk[w][1]=q0; sm.c.kpk[w][2]=q1; sm.c.kpk[w][3]=q2;
        sm.c.kpk[w][4]=q3; sm.c.kpk[w][5]=er; sm.c.kpk[w][6]=wvc; sm.c.kpk[w][7]=0.f;
        float s0 = wredsum(wk*wk);
        float s1 = wredsum(q0*q0);
        float s2 = wredsum(q1*q1);
        float s3 = wredsum(q2*q2);
        float s4 = wredsum(q3*q3);
        if (w == 0) {
          sm.c.scal[0] = fmaxf(sqrtf(s0), EPSV);
          sm.c.scal[1] = fmaxf(sqrtf(s1), EPSV);
          sm.c.scal[2] = fmaxf(sqrtf(s2), EPSV);
          sm.c.scal[3] = fmaxf(sqrtf(s3), EPSV);
          sm.c.scal[4] = fmaxf(sqrtf(s4), EPSV);
        }
      }
      __syncthreads();

      const int n  = tid & 127;
      const int wh = tid >> 7;

      // pass1: write-key dot + pre-update norm
      {
        float dotw = 0.f, q = 0.f;
        const int w0 = wh*16;
        #pragma unroll
        for (int w = 0; w < 16; ++w) {
          float m = memS[n][w0+w];
          dotw += sm.c.kpk[w0+w][0]*m;
          q    += m*m;
        }
        sm.c.dH[wh][n] = dotw;
        sm.c.qH[wh][n] = q;
      }
      __syncthreads();

      // write softmax over 128 slots
      float a_n = 0.f, e_n = 0.f;
      const float wstr = softp(sm.c.ifcS[324]) + 1.f;
      if (tid < 128) {
        float dot = sm.c.dH[0][n] + sm.c.dH[1][n] + sm.c.dH[2][n] + sm.c.dH[3][n];
        float q2  = sm.c.qH[0][n] + sm.c.qH[1][n] + sm.c.qH[2][n] + sm.c.qH[3][n];
        a_n = wstr * dot / (sm.c.scal[0] * fmaxf(sqrtf(q2), EPSV));
        float mx = wredmax(a_n);
        if ((tid & 63) == 0) sm.c.red2[tid>>6] = mx;
      }
      __syncthreads();
      if (tid < 128) {
        float mx = fmaxf(sm.c.red2[0], sm.c.red2[1]);
        e_n = expf(a_n - mx);
        float s = wredsum(e_n);
        if ((tid & 63) == 0) sm.c.red2[4 + (tid>>6)] = s;
      }
      __syncthreads();
      if (tid < 128)
        sm.c.wwS[n] = e_n / (sm.c.red2[4] + sm.c.red2[5]);
      __syncthreads();

      // pass2: memory update + read-key dots + post norm
      {
        float ww_n = sm.c.wwS[n];
        float nrm=0.f, d0=0.f, d1=0.f, d2=0.f, d3=0.f;
        const int w0 = wh*16;
        #pragma unroll
        for (int w = 0; w < 16; ++w) {
          float4 k0 = *(const float4*)&sm.c.kpk[w0+w][0];
          float4 k1 = *(const float4*)&sm.c.kpk[w0+w][4];
          float m  = memS[n][w0+w];
          float mn = m*(1.f - ww_n*k1.y) + ww_n*k1.z;
          memS[n][w0+w] = mn;
          nrm += mn*mn;
          d0 += k0.y*mn; d1 += k0.z*mn; d2 += k0.w*mn; d3 += k1.x*mn;
        }
        sm.c.nH[wh][n] = nrm;
        sm.c.drH[wh][0][n]=d0; sm.c.drH[wh][1][n]=d1;
        sm.c.drH[wh][2][n]=d2; sm.c.drH[wh][3][n]=d3;
      }
      __syncthreads();

      // read scores
      if (tid < 128) {
        float nrm = sm.c.nH[0][n] + sm.c.nH[1][n] + sm.c.nH[2][n] + sm.c.nH[3][n];
        float inm = 1.f / fmaxf(sqrtf(nrm), EPSV);
        #pragma unroll
        for (int r = 0; r < RR_; ++r) {
          float rstr = softp(sm.c.ifcS[256+r]) + 1.f;
          float dr = sm.c.drH[0][r][n] + sm.c.drH[1][r][n]
                   + sm.c.drH[2][r][n] + sm.c.drH[3][r][n];
          sm.c.rwS[r][n] = rstr * dr * inm / sm.c.scal[1+r];
        }
      }
      __syncthreads();

      // read softmaxes: waves 0..3 = heads
      if (tid < 256) {
        float v0 = sm.c.rwS[wv][b], v1 = sm.c.rwS[wv][b+64];
        float mx = wredmax(fmaxf(v0, v1));
        float e0 = expf(v0-mx), e1 = expf(v1-mx);
        float s  = wredsum(e0+e1);
        sm.c.rwS[wv][b]    = e0/s;
        sm.c.rwS[wv][b+64] = e1/s;
      }
      __syncthreads();

      // rv partials: wave wv -> head wv>>1, n-half wv&1
      {
        const int r  = wv >> 1;
        const int n0 = (wv & 1) * 64;
        float acc = 0.f;
        #pragma unroll 4
        for (int n2 = n0; n2 < n0 + 64; n2 += 4) {
          float4 r4 = *(const float4*)&sm.c.rwS[r][n2];
          acc += r4.x*memS[n2][b]   + r4.y*memS[n2+1][b]
               + r4.z*memS[n2+2][b] + r4.w*memS[n2+3][b];
        }
        sm.c.rvH[wv][b] = acc;
      }
      __syncthreads();
      if (tid < 256) {
        const int r = tid >> 6;
        float acc = sm.c.rvH[2*r][b] + sm.c.rvH[2*r+1][b];
        const int k = r*64 + b;
        cstore1(p.rvp + (k>>2)*256 + bb*4 + (k&3), acc);
      }
    }
    gridbar(p.bar, ++bk);
  }

  // ================= Output projection (last step only) =================
  if (bi < 64) {
    const int o0 = bi*4;
    if (tid < 256) {
      float acc[4] = {0.f, 0.f, 0.f, 0.f};
      #pragma unroll 4
      for (int kk = 0; kk < 48; ++kk) {
        const int k = wv*192 + kk*4;
        const float* a8 = (k < 512)
          ? (p.hp  + (((k    )>>2)*64 + b)*4)    // TT even -> final h in hp[0]
          : (p.rvp + (((k-512)>>2)*64 + b)*4);
        float2 alo = cload2(a8);
        float2 ahi = cload2(a8 + 2);
        #pragma unroll
        for (int r = 0; r < 4; ++r) {
          float4 w = *(const float4*)(p.Wout + (size_t)(o0+r)*(HH_ + RR_*WWID_) + k);
          acc[r] += w.x*alo.x + w.y*alo.y + w.z*ahi.x + w.w*ahi.y;
        }
      }
      #pragma unroll
      for (int r = 0; r < 4; ++r) sm.redO[wv][r][b] = acc[r];
    }
    __syncthreads();
    if (tid < 64) {
      float4 o4;
      float* po = (float*)&o4;
      #pragma unroll
      for (int r = 0; r < 4; ++r)
        po[r] = sm.redO[0][r][b] + sm.redO[1][r][b] + sm.redO[2][r][b]
              + sm.redO[3][r][b] + p.bout[o0+r];
      *(float4*)(p.out + (size_t)b*DOUT_ + o0) = o4;
    }
  }
}

extern "C" void kernel_launch(void* const* d_in, const int* in_sizes, int n_in,
                              void* d_out, int out_size, void* d_ws, size_t ws_size,
                              hipStream_t stream)
{
  Params prm;
  prm.x    = (const float*)d_in[0];
  prm.Wih  = (const float*)d_in[1];
  prm.Whh  = (const float*)d_in[2];
  prm.bih  = (const float*)d_in[3];
  prm.bhh  = (const float*)d_in[4];
  const float* Wint = (const float*)d_in[5];
  prm.bint = (const float*)d_in[6];
  prm.Wout = (const float*)d_in[7];
  prm.bout = (const float*)d_in[8];
  prm.out  = (float*)d_out;

  float* ws = (float*)d_ws;
  size_t off = 0;
  prm.hp   = ws + off; off += 2*32768;
  prm.rvp  = ws + off; off += 16384;
  prm.WiT4 = ws + off; off += (size_t)128*OSTR*4;
  prm.bar  = (unsigned*)(ws + off); off += 2048;

  k_prep_w<<<453, 128, 0, stream>>>(Wint, prm.WiT4);
  k_initbar<<<5, 256, 0, stream>>>(prm.bar);
  k_persist<<<NBLK, NTHR, 0, stream>>>(prm);
}

// Round 14
// 8318.429 us; speedup vs baseline: 1.1537x; 1.0292x over previous
//
#include <hip/hip_runtime.h>
#include <math.h>

#define BB_   64
#define TT_   256
#define DIN_  256
#define HH_   512
#define NMEM_ 128
#define WWID_ 64
#define RR_   4
#define DOUT_ 256
#define CTRL_ 512
#define EPSV  1e-8f
#define NBLK  256
#define NTHR  512
#define OSTR  456   // W_intT4 o-stride
#define MPAD  65    // padded mem stride

__device__ __forceinline__ float sigm(float x){ return 1.f/(1.f+expf(-x)); }
__device__ __forceinline__ float softp(float x){ return (x>20.f)? x : log1pf(expf(x)); }
__device__ __forceinline__ float wredsum(float v){
  #pragma unroll
  for (int o=32;o>0;o>>=1) v += __shfl_xor(v,o,64);
  return v;
}
__device__ __forceinline__ float wredmax(float v){
  #pragma unroll
  for (int o=32;o>0;o>>=1) v = fmaxf(v, __shfl_xor(v,o,64));
  return v;
}

// ---- LLC-coherent accessors: relaxed agent-scope atomics (bypass per-XCD L2) ----
__device__ __forceinline__ float2 cload2(const float* p){
  unsigned long long u = __hip_atomic_load((const unsigned long long*)p,
                          __ATOMIC_RELAXED, __HIP_MEMORY_SCOPE_AGENT);
  float2 r; __builtin_memcpy(&r, &u, 8); return r;
}
__device__ __forceinline__ void cstore2(float* p, float2 v){
  unsigned long long u; __builtin_memcpy(&u, &v, 8);
  __hip_atomic_store((unsigned long long*)p, u, __ATOMIC_RELAXED,
                     __HIP_MEMORY_SCOPE_AGENT);
}
__device__ __forceinline__ void cstore1(float* p, float v){
  unsigned u; __builtin_memcpy(&u, &v, 4);
  __hip_atomic_store((unsigned*)p, u, __ATOMIC_RELAXED, __HIP_MEMORY_SCOPE_AGENT);
}
__device__ __forceinline__ unsigned cloadu(const unsigned* p){
  return __hip_atomic_load(p, __ATOMIC_RELAXED, __HIP_MEMORY_SCOPE_AGENT);
}
__device__ __forceinline__ void cincr(unsigned* p){
  __hip_atomic_fetch_add(p, 1u, __ATOMIC_RELAXED, __HIP_MEMORY_SCOPE_AGENT);
}

__global__ void k_initbar(unsigned* bar){
  int i = blockIdx.x*256 + threadIdx.x;
  if (i < 576)
    __hip_atomic_store(bar + i, 0u, __ATOMIC_RELAXED, __HIP_MEMORY_SCOPE_AGENT);
}

// one-time: W_intT4[kq][o][c] = W_int[o][4kq+c]
__global__ void k_prep_w(const float* __restrict__ Wint, float* __restrict__ WiT4){
  const int o  = blockIdx.x;
  const int kq = threadIdx.x;
  float4 v = *(const float4*)(Wint + (size_t)o*HH_ + 4*kq);
  *(float4*)(WiT4 + ((size_t)kq*OSTR + o)*4) = v;
}

struct Params {
  const float *x, *Wih, *Whh, *bih, *bhh, *bint, *Wout, *bout;
  float *out;
  float *hp;     // 2*32768 (h packed [j/4][b][4])
  float *rvp;    // 16384
  float *WiT4;   // 128*456*4
  unsigned *bar; // colA[c]@c*32, colC[c]@256+c*32, initctr@512
};

union __align__(16) SMu {
  struct {
    float4 actS[2048];          // 32 KB: [kq][bl] staged acts (8 batches)
    float  red[4][4][16][8];    // 8 KB:  [ks][g][jl][bl]
  } a;
  float redO[4][4][64];
  struct {
    float hS[HH_];
    float ifcS[OSTR];
    float kpk[WWID_][8];
    float dH[4][NMEM_];
    float qH[4][NMEM_];
    float nH[4][NMEM_];
    float drH[4][RR_][NMEM_];
    float wwS[NMEM_];
    float rwS[RR_][NMEM_];
    float rvH[8][64];
    float scal[8];
    float red2[8];
  } c;
};

__launch_bounds__(NTHR, 2)
__global__ void k_persist(Params p)
{
  __shared__ SMu sm;
  __shared__ float memS[NMEM_][MPAD];

  const int bi  = blockIdx.x;
  const int tid = threadIdx.x;
  const int b   = tid & 63;            // BC/epilogue lane
  const int wv  = tid >> 6;            // BC/epilogue wave
  const int rg  = bi & 31;             // row-group: 16 hidden units
  const int col = bi >> 5;             // batch column: 8 batches
  const int j0  = rg*16;
  const int B0  = col*8;
  const bool isBC = (rg < 8);          // 8 BC blocks per column
  const int bb  = col*8 + rg;          // BC batch (own column), valid if isBC

  unsigned* colA = p.bar + col*32;
  unsigned* colC = p.bar + 256 + col*32;

  // Phase A thread mapping (round-12 proven)
  const int ksA = tid >> 7;            // 0..3 K-slice of 256
  const int jlA = (tid >> 3) & 15;     // 0..15 hidden unit
  const int blA = tid & 7;             // 0..7 batch lane

  float c_reg = 0.f;                   // LSTM cell state (tid<128: (jl,bl))

  const float* wbg[4];
  {
    const float* wsrc = (ksA < 2) ? p.Wih : p.Whh;
    const int koff = (ksA & 1) * 256;
    #pragma unroll
    for (int g = 0; g < 4; ++g)
      wbg[g] = wsrc + (size_t)(g*HH_ + j0 + jlA)*CTRL_ + koff;
  }

  float bsum[4];
  if (tid < 128) {
    const int j = j0 + (tid >> 3);
    #pragma unroll
    for (int g = 0; g < 4; ++g)
      bsum[g] = p.bih[g*HH_ + j] + p.bhh[g*HH_ + j];
  }
  float bintR = 0.f;
  if (isBC && tid < 453) bintR = p.bint[tid];

  // ---- init: zero h0/rv, zero memS ----
  {
    const float2 zz = make_float2(0.f, 0.f);
    const int gt = bi*NTHR + tid;
    if      (gt < 16384) cstore2(p.hp  + 2*gt,         zz);
    else if (gt < 24576) cstore2(p.rvp + 2*(gt-16384), zz);
    if (isBC)
      for (int i = tid; i < NMEM_*MPAD; i += NTHR)
        ((float*)memS)[i] = 0.f;
  }
  // one-time global rendezvous (init visibility; 256 blocks always resident)
  __syncthreads();
  if (tid == 0) {
    cincr(p.bar + 512);
    while (cloadu(p.bar + 512) < (unsigned)NBLK) __builtin_amdgcn_s_sleep(2);
  }
  __syncthreads();

  for (int t = 0; t < TT_; ++t) {
    const int cur = t & 1, nxt = cur ^ 1;
    const float* hR = p.hp + cur*32768;
    float*       hW = p.hp + nxt*32768;

    // ---- wait: own column's rv(t-1) ready (transitively h(t) too) ----
    if (t > 0) {
      if (tid == 0)
        while (cloadu(colC) < 8u*(unsigned)t) __builtin_amdgcn_s_sleep(1);
      __syncthreads();
    }

    // ================= Phase A: gates GEMM + LSTM =================
    {
      // stage acts for this block's 8 batches: actS[kq][bl]
      #pragma unroll
      for (int i = 0; i < 4; ++i) {
        const int idx = tid + 512*i;
        const int kq = idx >> 3, bl = idx & 7, bg = B0 + bl;
        float4 v;
        if (kq < 64) {               // x: immutable input, plain cached load
          v = *(const float4*)(p.x + (size_t)bg*(TT_*DIN_)
                               + (size_t)t*DIN_ + kq*4);
        } else if (kq < 128) {       // rv: LLC-coherent
          const float* s = p.rvp + (kq-64)*256 + bg*4;
          float2 lo = cload2(s), hi = cload2(s + 2);
          v = make_float4(lo.x, lo.y, hi.x, hi.y);
        } else {                     // h: LLC-coherent
          const float* s = hR + (kq-128)*256 + bg*4;
          float2 lo = cload2(s), hi = cload2(s + 2);
          v = make_float4(lo.x, lo.y, hi.x, hi.y);
        }
        sm.a.actS[idx] = v;
      }
      __syncthreads();

      float4 ac[4];
      #pragma unroll
      for (int g = 0; g < 4; ++g) ac[g] = make_float4(0.f, 0.f, 0.f, 0.f);

      const int kbase = ksA*64;
      #pragma unroll 4
      for (int i = 0; i < 64; ++i) {
        float4 a = sm.a.actS[(kbase + i)*8 + blA];   // b128 broadcast
        #pragma unroll
        for (int g = 0; g < 4; ++g) {
          float4 w = *(const float4*)(wbg[g] + (i << 2));  // uniform, L2-warm
          ac[g].x += w.x*a.x; ac[g].y += w.y*a.y;
          ac[g].z += w.z*a.z; ac[g].w += w.w*a.w;
        }
      }
      #pragma unroll
      for (int g = 0; g < 4; ++g)
        sm.a.red[ksA][g][jlA][blA] = (ac[g].x + ac[g].y) + (ac[g].z + ac[g].w);
      __syncthreads();

      if (tid < 128) {
        const int jl = tid >> 3, bl = tid & 7;
        float gs[4];
        #pragma unroll
        for (int g = 0; g < 4; ++g)
          gs[g] = sm.a.red[0][g][jl][bl] + sm.a.red[1][g][jl][bl]
                + sm.a.red[2][g][jl][bl] + sm.a.red[3][g][jl][bl] + bsum[g];
        float cn = sigm(gs[1])*c_reg + sigm(gs[0])*tanhf(gs[2]);
        c_reg = cn;
        float hn = sigm(gs[3])*tanhf(cn);
        const int j = j0 + jl, bg = B0 + bl;
        cstore1(hW + (j>>2)*256 + bg*4 + (j&3), hn);
      }
    }
    __syncthreads();                   // drain h stores
    if (tid == 0) cincr(colA);

    // ====== BC (duty blocks rg<8): iface + content addressing ======
    if (isBC) {
      if (tid == 0)
        while (cloadu(colA) < 32u*(unsigned)(t+1)) __builtin_amdgcn_s_sleep(1);
      __syncthreads();

      if (tid < 128) {
        const float* hsrc = hW + tid*256 + bb*4;
        float2 lo = cload2(hsrc), hi = cload2(hsrc + 2);
        sm.c.hS[4*tid]   = lo.x; sm.c.hS[4*tid+1] = lo.y;
        sm.c.hS[4*tid+2] = hi.x; sm.c.hS[4*tid+3] = hi.y;
      }
      __syncthreads();
      {
        const int o = (tid < 453) ? tid : 452;
        float a0 = bintR, a1 = 0.f, a2 = 0.f, a3 = 0.f;
        #pragma unroll 8
        for (int kq = 0; kq < 128; ++kq) {
          float4 w  = *(const float4*)(p.WiT4 + ((size_t)kq*OSTR + o)*4);
          float4 h4 = *(const float4*)&sm.c.hS[kq << 2];
          a0 += w.x*h4.x; a1 += w.y*h4.y; a2 += w.z*h4.z; a3 += w.w*h4.w;
        }
        if (tid < 453) sm.c.ifcS[tid] = (a0 + a1) + (a2 + a3);
      }
      __syncthreads();

      // key pack + key norms (wave 0)
      if (tid < 64) {
        const int w = tid;
        float wk = sm.c.ifcS[260+w];
        float q0 = sm.c.ifcS[w],      q1 = sm.c.ifcS[64+w];
        float q2 = sm.c.ifcS[128+w],  q3 = sm.c.ifcS[192+w];
        float er  = sigm(sm.c.ifcS[325+w]);
        float wvc = sm.c.ifcS[389+w];
        sm.c.kpk[w][0]=wk; sm.c.kpk[w][1]=q0; sm.c.kpk[w][2]=q1; sm.c.kpk[w][3]=q2;
        sm.c.kpk[w][4]=q3; sm.c.kpk[w][5]=er; sm.c.kpk[w][6]=wvc; sm.c.kpk[w][7]=0.f;
        float s0 = wredsum(wk*wk);
        float s1 = wredsum(q0*q0);
        float s2 = wredsum(q1*q1);
        float s3 = wredsum(q2*q2);
        float s4 = wredsum(q3*q3);
        if (w == 0) {
          sm.c.scal[0] = fmaxf(sqrtf(s0), EPSV);
          sm.c.scal[1] = fmaxf(sqrtf(s1), EPSV);
          sm.c.scal[2] = fmaxf(sqrtf(s2), EPSV);
          sm.c.scal[3] = fmaxf(sqrtf(s3), EPSV);
          sm.c.scal[4] = fmaxf(sqrtf(s4), EPSV);
        }
      }
      __syncthreads();

      const int n  = tid & 127;
      const int wh = tid >> 7;

      // pass1: write-key dot + pre-update norm
      {
        float dotw = 0.f, q = 0.f;
        const int w0 = wh*16;
        #pragma unroll
        for (int w = 0; w < 16; ++w) {
          float m = memS[n][w0+w];
          dotw += sm.c.kpk[w0+w][0]*m;
          q    += m*m;
        }
        sm.c.dH[wh][n] = dotw;
        sm.c.qH[wh][n] = q;
      }
      __syncthreads();

      // write softmax over 128 slots
      float a_n = 0.f, e_n = 0.f;
      const float wstr = softp(sm.c.ifcS[324]) + 1.f;
      if (tid < 128) {
        float dot = sm.c.dH[0][n] + sm.c.dH[1][n] + sm.c.dH[2][n] + sm.c.dH[3][n];
        float q2  = sm.c.qH[0][n] + sm.c.qH[1][n] + sm.c.qH[2][n] + sm.c.qH[3][n];
        a_n = wstr * dot / (sm.c.scal[0] * fmaxf(sqrtf(q2), EPSV));
        float mx = wredmax(a_n);
        if ((tid & 63) == 0) sm.c.red2[tid>>6] = mx;
      }
      __syncthreads();
      if (tid < 128) {
        float mx = fmaxf(sm.c.red2[0], sm.c.red2[1]);
        e_n = expf(a_n - mx);
        float s = wredsum(e_n);
        if ((tid & 63) == 0) sm.c.red2[4 + (tid>>6)] = s;
      }
      __syncthreads();
      if (tid < 128)
        sm.c.wwS[n] = e_n / (sm.c.red2[4] + sm.c.red2[5]);
      __syncthreads();

      // pass2: memory update + read-key dots + post norm
      {
        float ww_n = sm.c.wwS[n];
        float nrm=0.f, d0=0.f, d1=0.f, d2=0.f, d3=0.f;
        const int w0 = wh*16;
        #pragma unroll
        for (int w = 0; w < 16; ++w) {
          float4 k0 = *(const float4*)&sm.c.kpk[w0+w][0];
          float4 k1 = *(const float4*)&sm.c.kpk[w0+w][4];
          float m  = memS[n][w0+w];
          float mn = m*(1.f - ww_n*k1.y) + ww_n*k1.z;
          memS[n][w0+w] = mn;
          nrm += mn*mn;
          d0 += k0.y*mn; d1 += k0.z*mn; d2 += k0.w*mn; d3 += k1.x*mn;
        }
        sm.c.nH[wh][n] = nrm;
        sm.c.drH[wh][0][n]=d0; sm.c.drH[wh][1][n]=d1;
        sm.c.drH[wh][2][n]=d2; sm.c.drH[wh][3][n]=d3;
      }
      __syncthreads();

      // read scores
      if (tid < 128) {
        float nrm = sm.c.nH[0][n] + sm.c.nH[1][n] + sm.c.nH[2][n] + sm.c.nH[3][n];
        float inm = 1.f / fmaxf(sqrtf(nrm), EPSV);
        #pragma unroll
        for (int r = 0; r < RR_; ++r) {
          float rstr = softp(sm.c.ifcS[256+r]) + 1.f;
          float dr = sm.c.drH[0][r][n] + sm.c.drH[1][r][n]
                   + sm.c.drH[2][r][n] + sm.c.drH[3][r][n];
          sm.c.rwS[r][n] = rstr * dr * inm / sm.c.scal[1+r];
        }
      }
      __syncthreads();

      // read softmaxes: waves 0..3 = heads
      if (tid < 256) {
        float v0 = sm.c.rwS[wv][b], v1 = sm.c.rwS[wv][b+64];
        float mx = wredmax(fmaxf(v0, v1));
        float e0 = expf(v0-mx), e1 = expf(v1-mx);
        float s  = wredsum(e0+e1);
        sm.c.rwS[wv][b]    = e0/s;
        sm.c.rwS[wv][b+64] = e1/s;
      }
      __syncthreads();

      // rv partials: wave wv -> head wv>>1, n-half wv&1
      {
        const int r  = wv >> 1;
        const int n0 = (wv & 1) * 64;
        float acc = 0.f;
        #pragma unroll 4
        for (int n2 = n0; n2 < n0 + 64; n2 += 4) {
          float4 r4 = *(const float4*)&sm.c.rwS[r][n2];
          acc += r4.x*memS[n2][b]   + r4.y*memS[n2+1][b]
               + r4.z*memS[n2+2][b] + r4.w*memS[n2+3][b];
        }
        sm.c.rvH[wv][b] = acc;
      }
      __syncthreads();
      if (tid < 256) {
        const int r = tid >> 6;
        float acc = sm.c.rvH[2*r][b] + sm.c.rvH[2*r+1][b];
        const int k = r*64 + b;
        cstore1(p.rvp + (k>>2)*256 + bb*4 + (k&3), acc);
      }
      __syncthreads();                 // drain rv stores
      if (tid == 0) cincr(colC);
    }
  }

  // ================= Output projection (last step only) =================
  if (bi < 64) {
    if (tid == 0) {
      #pragma unroll
      for (int c2 = 0; c2 < 8; ++c2)
        while (cloadu(p.bar + 256 + c2*32) < 8u*(unsigned)TT_)
          __builtin_amdgcn_s_sleep(1);
    }
    __syncthreads();
    const int o0 = bi*4;
    if (tid < 256) {
      float acc[4] = {0.f, 0.f, 0.f, 0.f};
      #pragma unroll 4
      for (int kk = 0; kk < 48; ++kk) {
        const int k = wv*192 + kk*4;
        const float* a8 = (k < 512)
          ? (p.hp  + (((k    )>>2)*64 + b)*4)    // TT even -> final h in hp[0]
          : (p.rvp + (((k-512)>>2)*64 + b)*4);
        float2 alo = cload2(a8);
        float2 ahi = cload2(a8 + 2);
        #pragma unroll
        for (int r = 0; r < 4; ++r) {
          float4 w = *(const float4*)(p.Wout + (size_t)(o0+r)*(HH_ + RR_*WWID_) + k);
          acc[r] += w.x*alo.x + w.y*alo.y + w.z*ahi.x + w.w*ahi.y;
        }
      }
      #pragma unroll
      for (int r = 0; r < 4; ++r) sm.redO[wv][r][b] = acc[r];
    }
    __syncthreads();
    if (tid < 64) {
      float4 o4;
      float* po = (float*)&o4;
      #pragma unroll
      for (int r = 0; r < 4; ++r)
        po[r] = sm.redO[0][r][b] + sm.redO[1][r][b] + sm.redO[2][r][b]
              + sm.redO[3][r][b] + p.bout[o0+r];
      *(float4*)(p.out + (size_t)b*DOUT_ + o0) = o4;
    }
  }
}

extern "C" void kernel_launch(void* const* d_in, const int* in_sizes, int n_in,
                              void* d_out, int out_size, void* d_ws, size_t ws_size,
                              hipStream_t stream)
{
  Params prm;
  prm.x    = (const float*)d_in[0];
  prm.Wih  = (const float*)d_in[1];
  prm.Whh  = (const float*)d_in[2];
  prm.bih  = (const float*)d_in[3];
  prm.bhh  = (const float*)d_in[4];
  const float* Wint = (const float*)d_in[5];
  prm.bint = (const float*)d_in[6];
  prm.Wout = (const float*)d_in[7];
  prm.bout = (const float*)d_in[8];
  prm.out  = (float*)d_out;

  float* ws = (float*)d_ws;
  size_t off = 0;
  prm.hp   = ws + off; off += 2*32768;
  prm.rvp  = ws + off; off += 16384;
  prm.WiT4 = ws + off; off += (size_t)128*OSTR*4;
  prm.bar  = (unsigned*)(ws + off); off += 1024;

  k_prep_w<<<453, 128, 0, stream>>>(Wint, prm.WiT4);
  k_initbar<<<3, 256, 0, stream>>>(prm.bar);
  k_persist<<<NBLK, NTHR, 0, stream>>>(prm);
}